// Round 10
// baseline (383.800 us; speedup 1.0000x reference)
//
#include <hip/hip_runtime.h>
#include <math.h>

#define NB 8
#define CDIM 256
#define HWD 1024
#define NH 8
#define HD 32
#define NN 102
#define GD 64

typedef __attribute__((ext_vector_type(8))) short bf16x8;
typedef __attribute__((ext_vector_type(4))) float f32x4;

__device__ inline short f2bf(float f) {
  union { float f; unsigned u; } v; v.f = f;
  unsigned r = v.u + 0x7fffu + ((v.u >> 16) & 1u);
  return (short)(r >> 16);
}
__device__ inline float bf2f(short s) {
  union { unsigned u; float f; } v;
  v.u = ((unsigned)(unsigned short)s) << 16;
  return v.f;
}

// ---------------- merged: split big weights hi/lo + bf16-transposed GAT weights ----------------
__global__ __launch_bounds__(256) void wsplitprep_k(const float* __restrict__ w_qkv,
                                                    const float* __restrict__ w_proj,
                                                    const float* __restrict__ g0W,
                                                    const float* __restrict__ g1W,
                                                    short* __restrict__ wqh, short* __restrict__ wql,
                                                    short* __restrict__ wph, short* __restrict__ wpl,
                                                    short* __restrict__ w0bT,
                                                    short* __restrict__ w1bT) {
  int bx = blockIdx.x;
  if (bx < 1024) {
    int t = bx * 256 + threadIdx.x;
    if (t < 196608) {
      float v = w_qkv[t];
      short hi = f2bf(v);
      wqh[t] = hi; wql[t] = f2bf(v - bf2f(hi));
    } else {
      int u = t - 196608;
      float v = w_proj[u];
      short hi = f2bf(v);
      wph[u] = hi; wpl[u] = f2bf(v - bf2f(hi));
    }
  } else {
    int t = (bx - 1024) * 256 + threadIdx.x;
    if (t < 16384) {
      int c = t >> 6, f = t & 63;
      w0bT[f * 256 + c] = f2bf(g0W[t]);
    } else if (t < 20480) {
      int u2 = t - 16384;
      int c = u2 >> 6, f = u2 & 63;
      w1bT[f * 64 + c] = f2bf(g1W[u2]);
    }
  }
}

// ---------------- x [b][c][p] -> xt hi/lo bf16 [b][p][c] ----------------
__global__ __launch_bounds__(256) void xsplit_k(const float* __restrict__ x,
                                                short* __restrict__ xth,
                                                short* __restrict__ xtl) {
  __shared__ float tile[64][65];
  int p0 = blockIdx.x * 64, c0 = blockIdx.y * 64, b = blockIdx.z;
  int t = threadIdx.x;
  {
    int g = t >> 6, p = t & 63;
#pragma unroll
    for (int i = 0; i < 16; ++i) {
      int cc = g * 16 + i;
      tile[cc][p] = x[((size_t)(b * 256 + c0 + cc)) * 1024 + p0 + p];
    }
  }
  __syncthreads();
  {
    int p = t >> 2, cs = (t & 3) * 16;
    size_t rb = ((size_t)(b * 1024 + p0 + p)) * 256 + c0 + cs;
#pragma unroll
    for (int g = 0; g < 4; ++g) {
      short4 hv, lv;
      float f0 = tile[cs + g * 4 + 0][p];
      float f1 = tile[cs + g * 4 + 1][p];
      float f2 = tile[cs + g * 4 + 2][p];
      float f3 = tile[cs + g * 4 + 3][p];
      hv.x = f2bf(f0); lv.x = f2bf(f0 - bf2f(hv.x));
      hv.y = f2bf(f1); lv.y = f2bf(f1 - bf2f(hv.y));
      hv.z = f2bf(f2); lv.z = f2bf(f2 - bf2f(hv.z));
      hv.w = f2bf(f3); lv.w = f2bf(f3 - bf2f(hv.w));
      *(short4*)(xth + rb + g * 4) = hv;
      *(short4*)(xtl + rb + g * 4) = lv;
    }
  }
}

// ---------------- importance = unbiased variance over channels ----------------
__global__ __launch_bounds__(256) void importance_k(const float* __restrict__ x,
                                                    float* __restrict__ imp) {
  __shared__ float red[8][33];
  int bp = blockIdx.x;
  int b = bp >> 5, p0 = (bp & 31) << 5;
  int t = threadIdx.x;
  int pl = t & 31, cg = t >> 5;
  const float* xp = x + (size_t)b * CDIM * HWD + p0 + pl;
  float s = 0.f;
  for (int cc = 0; cc < 32; ++cc) s += xp[(size_t)(cg * 32 + cc) * HWD];
  red[cg][pl] = s;
  __syncthreads();
  float tot = 0.f;
  for (int g = 0; g < 8; ++g) tot += red[g][pl];
  float mean = tot * (1.f / CDIM);
  __syncthreads();
  float v = 0.f;
  for (int cc = 0; cc < 32; ++cc) {
    float d = xp[(size_t)(cg * 32 + cc) * HWD] - mean;
    v += d * d;
  }
  red[cg][pl] = v;
  __syncthreads();
  if (t < 32) {
    float vv = 0.f;
    for (int g = 0; g < 8; ++g) vv += red[g][t];
    imp[b * 1024 + p0 + t] = vv * (1.f / (CDIM - 1));
  }
}

// ---------------- fused graph pipeline: all-LDS feats, fused coeffs, posadj tail ----------------
union GraphLDS {
  struct { float sv[1024]; int si[1024]; } tk;
  short featsB[NN * 264];
  struct { short alphaB[NN * 136]; short gB[NN * 72]; } ly;
};

__global__ __launch_bounds__(1024) void graph_k(
    const float* __restrict__ imp,
    const short* __restrict__ xth, const short* __restrict__ xtl,
    const short* __restrict__ w0bT, const short* __restrict__ w1bT,
    const float* __restrict__ g0as, const float* __restrict__ g0ad,
    const float* __restrict__ g0b,
    const float* __restrict__ g1as, const float* __restrict__ g1ad,
    const float* __restrict__ g1b,
    const float* __restrict__ wg2a, const float* __restrict__ bg2a,
    short* __restrict__ h0tG,
    float* __restrict__ gwp,                  // [b*8+h][1024] gate
    float* __restrict__ gwp2,                 // [b*8+h][1024] gate * log2(e)
    unsigned long long* __restrict__ posadj)  // [b*16+w][1024]
{
  __shared__ GraphLDS u;
  __shared__ ushort adjPack[NN][8];
  __shared__ float rnL[NN];
  __shared__ float asrcL[112], adstL[112];
  __shared__ int topiL[NN];
  __shared__ int nodeofL[1024];
  int b = blockIdx.x, t = threadIdx.x;
  int wv = t >> 6, lane = t & 63, quad = lane >> 4, l16 = lane & 15;
  short* hb = h0tG + (size_t)b * 64 * 128;

  // ---- phase T: top-102 bitonic sort (LDS-only) ----
  u.tk.sv[t] = imp[b * 1024 + t];
  u.tk.si[t] = t;
  nodeofL[t] = -1;
  for (int e = t; e < 64 * 26; e += 1024) hb[(e / 26) * 128 + 102 + (e % 26)] = 0;
  __syncthreads();
  for (int k = 2; k <= 1024; k <<= 1) {
    for (int j = k >> 1; j > 0; j >>= 1) {
      int ixj = t ^ j;
      if (ixj > t) {
        bool up = ((t & k) == 0);
        float a = u.tk.sv[t], c = u.tk.sv[ixj];
        if ((a > c) == up) {
          u.tk.sv[t] = c; u.tk.sv[ixj] = a;
          int ti = u.tk.si[t]; u.tk.si[t] = u.tk.si[ixj]; u.tk.si[ixj] = ti;
        }
      }
      __syncthreads();
    }
  }
  if (t >= 1024 - NN) {
    int n = 1023 - t;
    int idx = u.tk.si[t];
    topiL[n] = idx;
    nodeofL[idx] = n;
  }
  __syncthreads();

  // ---- phase F: coalesced gather from xth/xtl -> featsB LDS + 1/norm ----
  {
    int n = t >> 3, g = t & 7;
    if (n < NN) {
      int p = topiL[n];
      const short* xh = xth + ((size_t)(b * 1024 + p)) * 256 + g * 32;
      const short* xl = xtl + ((size_t)(b * 1024 + p)) * 256 + g * 32;
      float ss = 0.f;
#pragma unroll
      for (int c8 = 0; c8 < 4; ++c8) {
        bf16x8 hv = *(const bf16x8*)(xh + c8 * 8);
        bf16x8 lv = *(const bf16x8*)(xl + c8 * 8);
#pragma unroll
        for (int j = 0; j < 8; ++j) {
          float f = bf2f(hv[j]) + bf2f(lv[j]);
          ss += f * f;
        }
        *(bf16x8*)(&u.featsB[n * 264 + g * 32 + c8 * 8]) = hv;
      }
      ss += __shfl_xor(ss, 1);
      ss += __shfl_xor(ss, 2);
      ss += __shfl_xor(ss, 4);
      if (g == 0) rnL[n] = 1.f / fmaxf(sqrtf(ss), 1e-12f);
    }
  }
  __syncthreads();

  // ---- phase S: sim via MFMA (all-LDS) -> adjPack ----
  for (int tile = wv; tile < 49; tile += 16) {
    int I = tile / 7, J = tile % 7;
    int rA = I * 16 + l16; if (rA > NN - 1) rA = NN - 1;
    int rB = J * 16 + l16; if (rB > NN - 1) rB = NN - 1;
    const short* ap = &u.featsB[rA * 264 + quad * 8];
    const short* bp = &u.featsB[rB * 264 + quad * 8];
    f32x4 acc = (f32x4){0.f, 0.f, 0.f, 0.f};
#pragma unroll
    for (int kb = 0; kb < 8; ++kb)
      acc = __builtin_amdgcn_mfma_f32_16x16x32_bf16(*(const bf16x8*)(ap + kb * 32),
                                                    *(const bf16x8*)(bp + kb * 32), acc, 0, 0, 0);
#pragma unroll
    for (int r = 0; r < 4; ++r) {
      int i = I * 16 + quad * 4 + r, j = J * 16 + l16;
      bool e = (i < NN && j < NN) &&
               ((acc[r] * rnL[i < NN ? i : 0] * rnL[j < NN ? j : 0] > 0.6f) || (i == j));
      unsigned long long m = __ballot(e);
      if (l16 == 0 && i < NN) adjPack[i][J] = (ushort)((m >> (quad * 16)) & 0xFFFFull);
    }
  }
  __syncthreads();

  // ---- phase G0: h0 = feats @ W0 -> h0tG; asrc/adst fused ----
  if (wv < 7) {
    int mt = wv;
    int ar = mt * 16 + l16; if (ar > NN - 1) ar = NN - 1;
    const short* ap = &u.featsB[ar * 264 + quad * 8];
    float s1[4] = {0.f, 0.f, 0.f, 0.f}, s2[4] = {0.f, 0.f, 0.f, 0.f};
#pragma unroll
    for (int nt = 0; nt < 4; ++nt) {
      const short* bp = w0bT + (nt * 16 + l16) * 256 + quad * 8;
      f32x4 acc = (f32x4){0.f, 0.f, 0.f, 0.f};
#pragma unroll
      for (int kb = 0; kb < 8; ++kb)
        acc = __builtin_amdgcn_mfma_f32_16x16x32_bf16(*(const bf16x8*)(ap + kb * 32),
                                                      *(const bf16x8*)(bp + kb * 32), acc, 0, 0, 0);
      int f = nt * 16 + l16;
      float a_s = g0as[f], a_d = g0ad[f];
#pragma unroll
      for (int r = 0; r < 4; ++r) {
        int node = mt * 16 + quad * 4 + r;
        if (node < NN) hb[f * 128 + node] = f2bf(acc[r]);
        s1[r] += acc[r] * a_s;
        s2[r] += acc[r] * a_d;
      }
    }
#pragma unroll
    for (int r = 0; r < 4; ++r) {
      float v1 = s1[r], v2 = s2[r];
      v1 += __shfl_xor(v1, 1); v1 += __shfl_xor(v1, 2);
      v1 += __shfl_xor(v1, 4); v1 += __shfl_xor(v1, 8);
      v2 += __shfl_xor(v2, 1); v2 += __shfl_xor(v2, 2);
      v2 += __shfl_xor(v2, 4); v2 += __shfl_xor(v2, 8);
      int node = mt * 16 + quad * 4 + r;
      if (l16 == 0 && node < NN) { asrcL[node] = v1; adstL[node] = v2; }
    }
  }
  __syncthreads();

  for (int layer = 0; layer < 2; ++layer) {
    for (int i = wv; i < NN; i += 16) {
      float zi = adstL[i];
      int j1 = 64 + lane;
      bool e0 = (adjPack[i][lane >> 4] >> (lane & 15)) & 1;
      bool e1 = (j1 < NN) && ((adjPack[i][j1 >> 4] >> (j1 & 15)) & 1);
      float p0 = 0.f, p1 = 0.f;
      if (e0) { float z = zi + asrcL[lane]; p0 = __expf(z > 0.f ? z : 0.2f * z); }
      if (e1) { float z = zi + asrcL[j1]; p1 = __expf(z > 0.f ? z : 0.2f * z); }
      float s = p0 + p1;
      s += __shfl_xor(s, 1); s += __shfl_xor(s, 2); s += __shfl_xor(s, 4);
      s += __shfl_xor(s, 8); s += __shfl_xor(s, 16); s += __shfl_xor(s, 32);
      float inv = 1.f / s;
      u.ly.alphaB[i * 136 + lane] = f2bf(p0 * inv);
      u.ly.alphaB[i * 136 + 64 + lane] = f2bf(p1 * inv);
    }
    __syncthreads();
    {
      const float* bias = layer ? g1b : g0b;
      for (int tile = wv; tile < 28; tile += 16) {
        int mt = tile >> 2, nt = tile & 3;
        int ar = mt * 16 + l16; if (ar > NN - 1) ar = NN - 1;
        const short* ap = &u.ly.alphaB[ar * 136 + quad * 8];
        const short* bp = hb + (nt * 16 + l16) * 128 + quad * 8;
        f32x4 acc = (f32x4){0.f, 0.f, 0.f, 0.f};
#pragma unroll
        for (int kb = 0; kb < 4; ++kb)
          acc = __builtin_amdgcn_mfma_f32_16x16x32_bf16(*(const bf16x8*)(ap + kb * 32),
                                                        *(const bf16x8*)(bp + kb * 32), acc, 0, 0, 0);
        int f = nt * 16 + l16;
        float bv = bias[f];
#pragma unroll
        for (int r = 0; r < 4; ++r) {
          int i = mt * 16 + quad * 4 + r;
          if (i < NN) u.ly.gB[i * 72 + f] = f2bf(fmaxf(acc[r] + bv, 0.f));
        }
      }
    }
    __syncthreads();
    if (layer == 0) {
      if (wv < 7) {
        int mt = wv;
        int ar = mt * 16 + l16; if (ar > NN - 1) ar = NN - 1;
        const short* ap = &u.ly.gB[ar * 72 + quad * 8];
        float s1[4] = {0.f, 0.f, 0.f, 0.f}, s2[4] = {0.f, 0.f, 0.f, 0.f};
#pragma unroll
        for (int nt = 0; nt < 4; ++nt) {
          const short* bp = w1bT + (nt * 16 + l16) * 64 + quad * 8;
          f32x4 acc = (f32x4){0.f, 0.f, 0.f, 0.f};
#pragma unroll
          for (int kb = 0; kb < 2; ++kb)
            acc = __builtin_amdgcn_mfma_f32_16x16x32_bf16(*(const bf16x8*)(ap + kb * 32),
                                                          *(const bf16x8*)(bp + kb * 32), acc, 0, 0, 0);
          int f = nt * 16 + l16;
          float a_s = g1as[f], a_d = g1ad[f];
#pragma unroll
          for (int r = 0; r < 4; ++r) {
            int node = mt * 16 + quad * 4 + r;
            if (node < NN) hb[f * 128 + node] = f2bf(acc[r]);
            s1[r] += acc[r] * a_s;
            s2[r] += acc[r] * a_d;
          }
        }
#pragma unroll
        for (int r = 0; r < 4; ++r) {
          float v1 = s1[r], v2 = s2[r];
          v1 += __shfl_xor(v1, 1); v1 += __shfl_xor(v1, 2);
          v1 += __shfl_xor(v1, 4); v1 += __shfl_xor(v1, 8);
          v2 += __shfl_xor(v2, 1); v2 += __shfl_xor(v2, 2);
          v2 += __shfl_xor(v2, 4); v2 += __shfl_xor(v2, 8);
          int node = mt * 16 + quad * 4 + r;
          if (l16 == 0 && node < NN) { asrcL[node] = v1; adstL[node] = v2; }
        }
      }
      __syncthreads();
    }
  }

  // ---- gate: gwN = sigmoid(gB @ wg2a^T + b) ----
  float* wgL = (float*)&u.ly.alphaB[0];
  float* gwN = wgL + 512;
  if (t < 512) wgL[t] = wg2a[t];
  __syncthreads();
  if (t < NN * NH) {
    int n = t >> 3, h = t & 7;
    float z = bg2a[h];
#pragma unroll
    for (int c = 0; c < GD; ++c) z += bf2f(u.ly.gB[n * 72 + c]) * wgL[h * 64 + c];
    gwN[n * 8 + h] = 1.f / (1.f + __expf(-z));
  }
  __syncthreads();

  // ---- tail: position-space gwp/gwp2 + 1024-bit posadj rows ----
  {
    int p = t;
    int n = nodeofL[p];
#pragma unroll
    for (int h = 0; h < 8; ++h) {
      float g = (n >= 0) ? gwN[n * 8 + h] : 0.f;
      gwp[(size_t)(b * 8 + h) * 1024 + p] = g;
      gwp2[(size_t)(b * 8 + h) * 1024 + p] = g * 1.4426950408889634f;
    }
    unsigned long long m[16];
#pragma unroll
    for (int w = 0; w < 16; ++w) m[w] = 0;
    if (n >= 0) {
      for (int w = 0; w < 7; ++w) {
        unsigned bits = adjPack[n][w];
        while (bits) {
          int j = __ffs(bits) - 1;
          int pj = topiL[w * 16 + j];
          m[pj >> 6] |= 1ull << (pj & 63);
          bits &= bits - 1;
        }
      }
    }
#pragma unroll
    for (int w = 0; w < 16; ++w)
      posadj[((size_t)b * 16 + w) * 1024 + p] = m[w];
  }
}

// ---------------- QKV split-bf16 MFMA GEMM (32-col tiles, LDS-staged coalesced stores) ----------------
// Q is pre-scaled by hd^-0.5 * log2(e) (attn uses exp2). V^T stored with sigma32 key permutation.
__global__ __launch_bounds__(256, 4) void qkv_k(const short* __restrict__ xth,
                                                const short* __restrict__ xtl,
                                                const short* __restrict__ wqh,
                                                const short* __restrict__ wql,
                                                short* __restrict__ qhp, short* __restrict__ qlp,
                                                short* __restrict__ khp, short* __restrict__ klp,
                                                short* __restrict__ vtp) {
  __shared__ short st_s[4][16 * 40 * 2];
  int t = threadIdx.x, wid = t >> 6, lane = t & 63, quad = lane >> 4, l16 = lane & 15;
  int m0 = blockIdx.x * 64, y = blockIdx.y;
  int b = m0 >> 10;
  int row = m0 + wid * 16 + l16;
  int p_base = (m0 & 1023) + wid * 16;
  int qi = y >> 3, n0 = (y & 7) * 32;
  const short* wh = wqh + ((size_t)qi * 256 + n0) * 256;
  const short* wl = wql + ((size_t)qi * 256 + n0) * 256;
  const short* arh = xth + (size_t)row * 256 + quad * 8;
  const short* arl = xtl + (size_t)row * 256 + quad * 8;
  f32x4 acc[2];
  acc[0] = (f32x4){0.f, 0.f, 0.f, 0.f};
  acc[1] = (f32x4){0.f, 0.f, 0.f, 0.f};
#pragma unroll
  for (int kb = 0; kb < 8; ++kb) {
    bf16x8 ah = *(const bf16x8*)(arh + kb * 32);
    bf16x8 al = *(const bf16x8*)(arl + kb * 32);
#pragma unroll
    for (int nt = 0; nt < 2; ++nt) {
      size_t wo = (size_t)(nt * 16 + l16) * 256 + kb * 32 + quad * 8;
      bf16x8 bh_ = *(const bf16x8*)(wh + wo);
      bf16x8 bl_ = *(const bf16x8*)(wl + wo);
      acc[nt] = __builtin_amdgcn_mfma_f32_16x16x32_bf16(ah, bh_, acc[nt], 0, 0, 0);
      acc[nt] = __builtin_amdgcn_mfma_f32_16x16x32_bf16(ah, bl_, acc[nt], 0, 0, 0);
      acc[nt] = __builtin_amdgcn_mfma_f32_16x16x32_bf16(al, bh_, acc[nt], 0, 0, 0);
    }
  }
  int h = n0 >> 5;
  if (qi < 2) {
    const float scale = (qi == 0) ? 0.2550348595158156f : 1.f;  // hd^-0.5 * log2(e)
    short* hp = (qi == 0) ? qhp : khp;
    short* lp = (qi == 0) ? qlp : klp;
    short* vsh = &st_s[wid][0];
    short* vsl = &st_s[wid][640];
#pragma unroll
    for (int nt = 0; nt < 2; ++nt) {
      int d = nt * 16 + l16;
#pragma unroll
      for (int r = 0; r < 4; ++r) {
        float v = acc[nt][r] * scale;
        short hi = f2bf(v);
        vsh[(quad * 4 + r) * 40 + d] = hi;
        vsl[(quad * 4 + r) * 40 + d] = f2bf(v - bf2f(hi));
      }
    }
    int orow = lane >> 2, seg = lane & 3;
    size_t e = ((size_t)(b * 8 + h) * 1024 + p_base + orow) * 32 + seg * 8;
    *(bf16x8*)(hp + e) = *(const bf16x8*)(vsh + orow * 40 + seg * 8);
    *(bf16x8*)(lp + e) = *(const bf16x8*)(vsl + orow * 40 + seg * 8);
  } else {
    // V: block-level sigma32-permuted transpose -> vt[bh][d][...]
    short* vsv = &st_s[0][0];   // 32 x 72
#pragma unroll
    for (int nt = 0; nt < 2; ++nt) {
      int d = nt * 16 + l16;
#pragma unroll
      for (int r = 0; r < 4; ++r)
        vsv[d * 72 + (quad * 4 + r) * 2 + (wid & 1) + (wid >> 1) * 32] = f2bf(acc[nt][r]);
    }
    __syncthreads();
    int d = t >> 3, g = t & 7;
    size_t rb = ((size_t)(b * 8 + h) * 32 + d) * 1024 + (m0 & 1023) + g * 8;
    *(bf16x8*)(vtp + rb) = *(const bf16x8*)(vsv + d * 72 + g * 8);
  }
}

// ---------------- flash attention: 32-key chunks, register double-buffer prefetch, exp2 ----------------
__global__ __launch_bounds__(256, 4) void attn_k(const short* __restrict__ qh,
                                                 const short* __restrict__ ql,
                                                 const short* __restrict__ kh,
                                                 const short* __restrict__ kl,
                                                 const short* __restrict__ vt,
                                                 const float* __restrict__ gwp,
                                                 const float* __restrict__ gwp2,
                                                 const unsigned long long* __restrict__ posadj,
                                                 short* __restrict__ aoh,
                                                 short* __restrict__ aol) {
  __shared__ __align__(16) short p_s[4][16 * 72];  // P uses stride 40; overlay O f32 16x36
  __shared__ float aw_s[4][16];
  int t = threadIdx.x;
  int wid = t >> 6, lane = t & 63, quad = lane >> 4, l16 = lane & 15;
  int bh = blockIdx.x, b = bh >> 3, h = bh & 7;
  int q0 = blockIdx.y * 64 + wid * 16;
  size_t base = (size_t)bh * 32768;
  short* pw = &p_s[wid][0];
  float* aw = &aw_s[wid][0];

  size_t qoff = base + (size_t)(q0 + l16) * 32 + quad * 8;
  bf16x8 qhf = *(const bf16x8*)(qh + qoff);
  bf16x8 qlf = *(const bf16x8*)(ql + qoff);

  const float* gwpBH = gwp + (size_t)bh * 1024;
  const float* gwp2BH = gwp2 + (size_t)bh * 1024;
  const unsigned* pa32 = (const unsigned*)(posadj + (size_t)b * 16 * 1024);
  float grq[4];
#pragma unroll
  for (int r = 0; r < 4; ++r) grq[r] = gwp2BH[q0 + quad * 4 + r];

  f32x4 ot[2];
  ot[0] = (f32x4){0.f, 0.f, 0.f, 0.f};
  ot[1] = (f32x4){0.f, 0.f, 0.f, 0.f};
  float l_r[4] = {0.f, 0.f, 0.f, 0.f};

  // double-buffered chunk fragments (32 keys per chunk)
  bf16x8 khb[2][2], klb[2][2], vab[2][2];
  float gcb[2][2];
  unsigned mrb[2][4];

#define LOADCHUNK(pa_, ch_)                                                        \
  {                                                                                \
    int c0_ = (ch_) * 32;                                                          \
    _Pragma("unroll")                                                              \
    for (int ni = 0; ni < 2; ++ni) {                                               \
      size_t off_ = base + (size_t)(c0_ + ni * 16 + l16) * 32 + quad * 8;          \
      khb[pa_][ni] = *(const bf16x8*)(kh + off_);                                  \
      klb[pa_][ni] = *(const bf16x8*)(kl + off_);                                  \
      gcb[pa_][ni] = gwpBH[c0_ + ni * 16 + l16];                                   \
    }                                                                              \
    _Pragma("unroll")                                                              \
    for (int mi = 0; mi < 2; ++mi)                                                 \
      vab[pa_][mi] = *(const bf16x8*)(vt + base + (size_t)(mi * 16 + l16) * 1024 + \
                                      c0_ + quad * 8);                             \
    _Pragma("unroll")                                                              \
    for (int r = 0; r < 4; ++r)                                                    \
      mrb[pa_][r] = pa32[(((size_t)((ch_) >> 1) * 1024) + q0 + quad * 4 + r) * 2 + \
                         ((ch_) & 1)];                                             \
  }

  LOADCHUNK(0, 0)
#pragma unroll 2
  for (int ch = 0; ch < 32; ++ch) {
    int pa = ch & 1;
    if (ch < 31) LOADCHUNK(!pa, ch + 1)
    // S = Q K^T (split-bf16, scores pre-scaled to log2 units)
    f32x4 s[2];
#pragma unroll
    for (int ni = 0; ni < 2; ++ni) {
      f32x4 a = (f32x4){0.f, 0.f, 0.f, 0.f};
      a = __builtin_amdgcn_mfma_f32_16x16x32_bf16(qhf, khb[pa][ni], a, 0, 0, 0);
      a = __builtin_amdgcn_mfma_f32_16x16x32_bf16(qhf, klb[pa][ni], a, 0, 0, 0);
      a = __builtin_amdgcn_mfma_f32_16x16x32_bf16(qlf, khb[pa][ni], a, 0, 0, 0);
      s[ni] = a;
    }
    // graph modulation (bitmask + gates; grq carries log2e)
#pragma unroll
    for (int r = 0; r < 4; ++r) {
#pragma unroll
      for (int ni = 0; ni < 2; ++ni) {
        bool bit = (mrb[pa][r] >> (ni * 16 + l16)) & 1u;
        s[ni][r] += bit ? grq[r] * gcb[pa][ni] : 0.f;
      }
    }
    // p = exp2(s); store in sigma32 layout (key ni*16+l16 -> col l16*2+ni)
#pragma unroll
    for (int r = 0; r < 4; ++r) {
      float e0 = exp2f(s[0][r]);
      float e1 = exp2f(s[1][r]);
      l_r[r] += e0 + e1;
      short2 pq = {f2bf(e0), f2bf(e1)};
      *(short2*)(pw + (quad * 4 + r) * 40 + l16 * 2) = pq;
    }
    // PV: one K=32 MFMA per ot tile
    bf16x8 pb = *(const bf16x8*)(pw + l16 * 40 + quad * 8);
    ot[0] = __builtin_amdgcn_mfma_f32_16x16x32_bf16(vab[pa][0], pb, ot[0], 0, 0, 0);
    ot[1] = __builtin_amdgcn_mfma_f32_16x16x32_bf16(vab[pa][1], pb, ot[1], 0, 0, 0);
  }
#undef LOADCHUNK

  // final row-sum reduce, invert, transpose via per-wave LDS, hi/lo bf16 store
#pragma unroll
  for (int r = 0; r < 4; ++r) {
    float ls = l_r[r];
    ls += __shfl_xor(ls, 1);
    ls += __shfl_xor(ls, 2);
    ls += __shfl_xor(ls, 4);
    ls += __shfl_xor(ls, 8);
    if (l16 == 0) aw[quad * 4 + r] = 1.f / ls;
  }
  float li = aw[l16];
  ot[0] *= li;
  ot[1] *= li;
  float* os = (float*)pw;
#pragma unroll
  for (int mi = 0; mi < 2; ++mi)
#pragma unroll
    for (int r = 0; r < 4; ++r)
      os[l16 * 36 + mi * 16 + quad * 4 + r] = ot[mi][r];
  int qr2 = lane >> 2, dg = (lane & 3) * 8;
  float f[8];
  *(float4*)&f[0] = *(float4*)&os[qr2 * 36 + dg];
  *(float4*)&f[4] = *(float4*)&os[qr2 * 36 + dg + 4];
  bf16x8 hv, lv;
#pragma unroll
  for (int j = 0; j < 8; ++j) {
    hv[j] = f2bf(f[j]);
    lv[j] = f2bf(f[j] - bf2f(hv[j]));
  }
  size_t ob = (size_t)(b * 1024 + q0 + qr2) * 256 + h * 32 + dg;
  *(bf16x8*)(aoh + ob) = hv;
  *(bf16x8*)(aol + ob) = lv;
}

// ---------------- proj split-bf16 MFMA GEMM (32-col tiles) + bias + transposed store ----------------
__global__ __launch_bounds__(256, 4) void proj_k(const short* __restrict__ aoh,
                                                 const short* __restrict__ aol,
                                                 const short* __restrict__ wph,
                                                 const short* __restrict__ wpl,
                                                 const float* __restrict__ bias,
                                                 float* __restrict__ out) {
  __shared__ float os_s[4][32 * 20];
  int t = threadIdx.x, wid = t >> 6, lane = t & 63, quad = lane >> 4, l16 = lane & 15;
  int m0 = blockIdx.x * 64, n0 = blockIdx.y * 32;
  int b = m0 >> 10;
  int row = m0 + wid * 16 + l16;
  int p_base = (m0 & 1023) + wid * 16;
  const short* arh = aoh + (size_t)row * 256 + quad * 8;
  const short* arl = aol + (size_t)row * 256 + quad * 8;
  f32x4 acc[2];
  acc[0] = (f32x4){0.f, 0.f, 0.f, 0.f};
  acc[1] = (f32x4){0.f, 0.f, 0.f, 0.f};
#pragma unroll
  for (int kb = 0; kb < 8; ++kb) {
    bf16x8 ah = *(const bf16x8*)(arh + kb * 32);
    bf16x8 al = *(const bf16x8*)(arl + kb * 32);
#pragma unroll
    for (int nt = 0; nt < 2; ++nt) {
      size_t wo = (size_t)(n0 + nt * 16 + l16) * 256 + kb * 32 + quad * 8;
      bf16x8 bh_ = *(const bf16x8*)(wph + wo);
      bf16x8 bl_ = *(const bf16x8*)(wpl + wo);
      acc[nt] = __builtin_amdgcn_mfma_f32_16x16x32_bf16(ah, bh_, acc[nt], 0, 0, 0);
      acc[nt] = __builtin_amdgcn_mfma_f32_16x16x32_bf16(ah, bl_, acc[nt], 0, 0, 0);
      acc[nt] = __builtin_amdgcn_mfma_f32_16x16x32_bf16(al, bh_, acc[nt], 0, 0, 0);
    }
  }
  float* os = &os_s[wid][0];
#pragma unroll
  for (int nt = 0; nt < 2; ++nt) {
    float bv = bias[n0 + nt * 16 + l16];
#pragma unroll
    for (int r = 0; r < 4; ++r)
      os[(nt * 16 + l16) * 20 + quad * 4 + r] = acc[nt][r] + bv;
  }
  int cl = lane >> 1, hf = lane & 1;
  int c = n0 + cl;
  float* orow = out + ((size_t)(b * 256 + c)) * 1024 + p_base;
  *(float4*)(orow + hf * 8) = *(float4*)&os[cl * 20 + hf * 8];
  *(float4*)(orow + hf * 8 + 4) = *(float4*)&os[cl * 20 + hf * 8 + 4];
}

extern "C" void kernel_launch(void* const* d_in, const int* in_sizes, int n_in,
                              void* d_out, int out_size, void* d_ws, size_t ws_size,
                              hipStream_t stream) {
  const float* x      = (const float*)d_in[0];
  const float* w_qkv  = (const float*)d_in[1];
  const float* w_proj = (const float*)d_in[2];
  const float* b_proj = (const float*)d_in[3];
  const float* g0W    = (const float*)d_in[4];
  const float* g0as   = (const float*)d_in[5];
  const float* g0ad   = (const float*)d_in[6];
  const float* g0b    = (const float*)d_in[7];
  const float* g1W    = (const float*)d_in[8];
  const float* g1as   = (const float*)d_in[9];
  const float* g1ad   = (const float*)d_in[10];
  const float* g1b    = (const float*)d_in[11];
  const float* wg2a   = (const float*)d_in[12];
  const float* bg2a   = (const float*)d_in[13];
  float* out = (float*)d_out;
  float* ws = (float*)d_ws;

  size_t o = 0;
  auto alloc = [&](size_t nf) { float* p = ws + o; o += (nf + 15) & ~(size_t)15; return p; };
  float* imp    = alloc(8 * 1024);
  short* w0bT   = (short*)alloc(256 * 64 / 2);
  short* w1bT   = (short*)alloc(64 * 64 / 2);
  short* h0tG   = (short*)alloc(8 * 64 * 128 / 2);
  float* gwp    = alloc(64 * 1024);
  float* gwp2   = alloc(64 * 1024);
  unsigned long long* posadj = (unsigned long long*)alloc(8 * 16 * 1024 * 2);
  short* xth    = (short*)alloc(1048576);
  short* xtl    = (short*)alloc(1048576);
  short* wqh    = (short*)alloc(98304);
  short* wql    = (short*)alloc(98304);
  short* wph    = (short*)alloc(32768);
  short* wpl    = (short*)alloc(32768);
  short* qh     = (short*)alloc(1048576);
  short* ql     = (short*)alloc(1048576);
  short* kh     = (short*)alloc(1048576);
  short* kl     = (short*)alloc(1048576);
  short* vt     = (short*)alloc(1048576);
  short* aoh    = (short*)alloc(1048576);
  short* aol    = (short*)alloc(1048576);
  if (ws_size < o * sizeof(float)) return;

  importance_k<<<256, 256, 0, stream>>>(x, imp);
  wsplitprep_k<<<1104, 256, 0, stream>>>(w_qkv, w_proj, g0W, g1W,
                                         wqh, wql, wph, wpl, w0bT, w1bT);
  xsplit_k<<<dim3(16, 4, 8), 256, 0, stream>>>(x, xth, xtl);
  graph_k<<<8, 1024, 0, stream>>>(imp, xth, xtl, w0bT, w1bT,
                                  g0as, g0ad, g0b, g1as, g1ad, g1b,
                                  wg2a, bg2a, h0tG, gwp, gwp2, posadj);
  qkv_k<<<dim3(128, 24), 256, 0, stream>>>(xth, xtl, wqh, wql, qh, ql, kh, kl, vt);
  attn_k<<<dim3(64, 16), 256, 0, stream>>>(qh, ql, kh, kl, vt, gwp, gwp2, posadj, aoh, aol);
  proj_k<<<dim3(128, 8), 256, 0, stream>>>(aoh, aol, wph, wpl, b_proj, out);
}

// Round 11
// 306.546 us; speedup vs baseline: 1.2520x; 1.2520x over previous
//
#include <hip/hip_runtime.h>
#include <math.h>

#define NB 8
#define CDIM 256
#define HWD 1024
#define NH 8
#define HD 32
#define NN 102
#define GD 64

typedef __attribute__((ext_vector_type(8))) short bf16x8;
typedef __attribute__((ext_vector_type(4))) float f32x4;

__device__ inline short f2bf(float f) {
  union { float f; unsigned u; } v; v.f = f;
  unsigned r = v.u + 0x7fffu + ((v.u >> 16) & 1u);
  return (short)(r >> 16);
}
__device__ inline float bf2f(short s) {
  union { unsigned u; float f; } v;
  v.u = ((unsigned)(unsigned short)s) << 16;
  return v.f;
}

// ---------------- merged: split big weights hi/lo + bf16-transposed GAT weights ----------------
__global__ __launch_bounds__(256) void wsplitprep_k(const float* __restrict__ w_qkv,
                                                    const float* __restrict__ w_proj,
                                                    const float* __restrict__ g0W,
                                                    const float* __restrict__ g1W,
                                                    short* __restrict__ wqh, short* __restrict__ wql,
                                                    short* __restrict__ wph, short* __restrict__ wpl,
                                                    short* __restrict__ w0bT,
                                                    short* __restrict__ w1bT) {
  int bx = blockIdx.x;
  if (bx < 1024) {
    int t = bx * 256 + threadIdx.x;
    if (t < 196608) {
      float v = w_qkv[t];
      short hi = f2bf(v);
      wqh[t] = hi; wql[t] = f2bf(v - bf2f(hi));
    } else {
      int u = t - 196608;
      float v = w_proj[u];
      short hi = f2bf(v);
      wph[u] = hi; wpl[u] = f2bf(v - bf2f(hi));
    }
  } else {
    int t = (bx - 1024) * 256 + threadIdx.x;
    if (t < 16384) {
      int c = t >> 6, f = t & 63;
      w0bT[f * 256 + c] = f2bf(g0W[t]);
    } else if (t < 20480) {
      int u2 = t - 16384;
      int c = u2 >> 6, f = u2 & 63;
      w1bT[f * 64 + c] = f2bf(g1W[u2]);
    }
  }
}

// ---------------- x [b][c][p] -> xt hi/lo bf16 [b][p][c] ----------------
__global__ __launch_bounds__(256) void xsplit_k(const float* __restrict__ x,
                                                short* __restrict__ xth,
                                                short* __restrict__ xtl) {
  __shared__ float tile[64][65];
  int p0 = blockIdx.x * 64, c0 = blockIdx.y * 64, b = blockIdx.z;
  int t = threadIdx.x;
  {
    int g = t >> 6, p = t & 63;
#pragma unroll
    for (int i = 0; i < 16; ++i) {
      int cc = g * 16 + i;
      tile[cc][p] = x[((size_t)(b * 256 + c0 + cc)) * 1024 + p0 + p];
    }
  }
  __syncthreads();
  {
    int p = t >> 2, cs = (t & 3) * 16;
    size_t rb = ((size_t)(b * 1024 + p0 + p)) * 256 + c0 + cs;
#pragma unroll
    for (int g = 0; g < 4; ++g) {
      short4 hv, lv;
      float f0 = tile[cs + g * 4 + 0][p];
      float f1 = tile[cs + g * 4 + 1][p];
      float f2 = tile[cs + g * 4 + 2][p];
      float f3 = tile[cs + g * 4 + 3][p];
      hv.x = f2bf(f0); lv.x = f2bf(f0 - bf2f(hv.x));
      hv.y = f2bf(f1); lv.y = f2bf(f1 - bf2f(hv.y));
      hv.z = f2bf(f2); lv.z = f2bf(f2 - bf2f(hv.z));
      hv.w = f2bf(f3); lv.w = f2bf(f3 - bf2f(hv.w));
      *(short4*)(xth + rb + g * 4) = hv;
      *(short4*)(xtl + rb + g * 4) = lv;
    }
  }
}

// ---------------- importance = unbiased variance over channels ----------------
__global__ __launch_bounds__(256) void importance_k(const float* __restrict__ x,
                                                    float* __restrict__ imp) {
  __shared__ float red[8][33];
  int bp = blockIdx.x;
  int b = bp >> 5, p0 = (bp & 31) << 5;
  int t = threadIdx.x;
  int pl = t & 31, cg = t >> 5;
  const float* xp = x + (size_t)b * CDIM * HWD + p0 + pl;
  float s = 0.f;
  for (int cc = 0; cc < 32; ++cc) s += xp[(size_t)(cg * 32 + cc) * HWD];
  red[cg][pl] = s;
  __syncthreads();
  float tot = 0.f;
  for (int g = 0; g < 8; ++g) tot += red[g][pl];
  float mean = tot * (1.f / CDIM);
  __syncthreads();
  float v = 0.f;
  for (int cc = 0; cc < 32; ++cc) {
    float d = xp[(size_t)(cg * 32 + cc) * HWD] - mean;
    v += d * d;
  }
  red[cg][pl] = v;
  __syncthreads();
  if (t < 32) {
    float vv = 0.f;
    for (int g = 0; g < 8; ++g) vv += red[g][t];
    imp[b * 1024 + p0 + t] = vv * (1.f / (CDIM - 1));
  }
}

// ---------------- fused graph pipeline: all-LDS feats, fused coeffs, posadj tail ----------------
union GraphLDS {
  struct { float sv[1024]; int si[1024]; } tk;
  short featsB[NN * 264];
  struct { short alphaB[NN * 136]; short gB[NN * 72]; } ly;
};

__global__ __launch_bounds__(1024) void graph_k(
    const float* __restrict__ imp,
    const short* __restrict__ xth, const short* __restrict__ xtl,
    const short* __restrict__ w0bT, const short* __restrict__ w1bT,
    const float* __restrict__ g0as, const float* __restrict__ g0ad,
    const float* __restrict__ g0b,
    const float* __restrict__ g1as, const float* __restrict__ g1ad,
    const float* __restrict__ g1b,
    const float* __restrict__ wg2a, const float* __restrict__ bg2a,
    short* __restrict__ h0tG,
    float* __restrict__ gwp,                  // [b*8+h][1024] gate
    float* __restrict__ gwp2,                 // [b*8+h][1024] gate * log2(e)
    unsigned long long* __restrict__ posadj)  // [b*16+w][1024]
{
  __shared__ GraphLDS u;
  __shared__ ushort adjPack[NN][8];
  __shared__ float rnL[NN];
  __shared__ float asrcL[112], adstL[112];
  __shared__ int topiL[NN];
  __shared__ int nodeofL[1024];
  int b = blockIdx.x, t = threadIdx.x;
  int wv = t >> 6, lane = t & 63, quad = lane >> 4, l16 = lane & 15;
  short* hb = h0tG + (size_t)b * 64 * 128;

  // ---- phase T: top-102 bitonic sort (LDS-only) ----
  u.tk.sv[t] = imp[b * 1024 + t];
  u.tk.si[t] = t;
  nodeofL[t] = -1;
  for (int e = t; e < 64 * 26; e += 1024) hb[(e / 26) * 128 + 102 + (e % 26)] = 0;
  __syncthreads();
  for (int k = 2; k <= 1024; k <<= 1) {
    for (int j = k >> 1; j > 0; j >>= 1) {
      int ixj = t ^ j;
      if (ixj > t) {
        bool up = ((t & k) == 0);
        float a = u.tk.sv[t], c = u.tk.sv[ixj];
        if ((a > c) == up) {
          u.tk.sv[t] = c; u.tk.sv[ixj] = a;
          int ti = u.tk.si[t]; u.tk.si[t] = u.tk.si[ixj]; u.tk.si[ixj] = ti;
        }
      }
      __syncthreads();
    }
  }
  if (t >= 1024 - NN) {
    int n = 1023 - t;
    int idx = u.tk.si[t];
    topiL[n] = idx;
    nodeofL[idx] = n;
  }
  __syncthreads();

  // ---- phase F: coalesced gather from xth/xtl -> featsB LDS + 1/norm ----
  {
    int n = t >> 3, g = t & 7;
    if (n < NN) {
      int p = topiL[n];
      const short* xh = xth + ((size_t)(b * 1024 + p)) * 256 + g * 32;
      const short* xl = xtl + ((size_t)(b * 1024 + p)) * 256 + g * 32;
      float ss = 0.f;
#pragma unroll
      for (int c8 = 0; c8 < 4; ++c8) {
        bf16x8 hv = *(const bf16x8*)(xh + c8 * 8);
        bf16x8 lv = *(const bf16x8*)(xl + c8 * 8);
#pragma unroll
        for (int j = 0; j < 8; ++j) {
          float f = bf2f(hv[j]) + bf2f(lv[j]);
          ss += f * f;
        }
        *(bf16x8*)(&u.featsB[n * 264 + g * 32 + c8 * 8]) = hv;
      }
      ss += __shfl_xor(ss, 1);
      ss += __shfl_xor(ss, 2);
      ss += __shfl_xor(ss, 4);
      if (g == 0) rnL[n] = 1.f / fmaxf(sqrtf(ss), 1e-12f);
    }
  }
  __syncthreads();

  // ---- phase S: sim via MFMA (all-LDS) -> adjPack ----
  for (int tile = wv; tile < 49; tile += 16) {
    int I = tile / 7, J = tile % 7;
    int rA = I * 16 + l16; if (rA > NN - 1) rA = NN - 1;
    int rB = J * 16 + l16; if (rB > NN - 1) rB = NN - 1;
    const short* ap = &u.featsB[rA * 264 + quad * 8];
    const short* bp = &u.featsB[rB * 264 + quad * 8];
    f32x4 acc = (f32x4){0.f, 0.f, 0.f, 0.f};
#pragma unroll
    for (int kb = 0; kb < 8; ++kb)
      acc = __builtin_amdgcn_mfma_f32_16x16x32_bf16(*(const bf16x8*)(ap + kb * 32),
                                                    *(const bf16x8*)(bp + kb * 32), acc, 0, 0, 0);
#pragma unroll
    for (int r = 0; r < 4; ++r) {
      int i = I * 16 + quad * 4 + r, j = J * 16 + l16;
      bool e = (i < NN && j < NN) &&
               ((acc[r] * rnL[i < NN ? i : 0] * rnL[j < NN ? j : 0] > 0.6f) || (i == j));
      unsigned long long m = __ballot(e);
      if (l16 == 0 && i < NN) adjPack[i][J] = (ushort)((m >> (quad * 16)) & 0xFFFFull);
    }
  }
  __syncthreads();

  // ---- phase G0: h0 = feats @ W0 -> h0tG; asrc/adst fused ----
  if (wv < 7) {
    int mt = wv;
    int ar = mt * 16 + l16; if (ar > NN - 1) ar = NN - 1;
    const short* ap = &u.featsB[ar * 264 + quad * 8];
    float s1[4] = {0.f, 0.f, 0.f, 0.f}, s2[4] = {0.f, 0.f, 0.f, 0.f};
#pragma unroll
    for (int nt = 0; nt < 4; ++nt) {
      const short* bp = w0bT + (nt * 16 + l16) * 256 + quad * 8;
      f32x4 acc = (f32x4){0.f, 0.f, 0.f, 0.f};
#pragma unroll
      for (int kb = 0; kb < 8; ++kb)
        acc = __builtin_amdgcn_mfma_f32_16x16x32_bf16(*(const bf16x8*)(ap + kb * 32),
                                                      *(const bf16x8*)(bp + kb * 32), acc, 0, 0, 0);
      int f = nt * 16 + l16;
      float a_s = g0as[f], a_d = g0ad[f];
#pragma unroll
      for (int r = 0; r < 4; ++r) {
        int node = mt * 16 + quad * 4 + r;
        if (node < NN) hb[f * 128 + node] = f2bf(acc[r]);
        s1[r] += acc[r] * a_s;
        s2[r] += acc[r] * a_d;
      }
    }
#pragma unroll
    for (int r = 0; r < 4; ++r) {
      float v1 = s1[r], v2 = s2[r];
      v1 += __shfl_xor(v1, 1); v1 += __shfl_xor(v1, 2);
      v1 += __shfl_xor(v1, 4); v1 += __shfl_xor(v1, 8);
      v2 += __shfl_xor(v2, 1); v2 += __shfl_xor(v2, 2);
      v2 += __shfl_xor(v2, 4); v2 += __shfl_xor(v2, 8);
      int node = mt * 16 + quad * 4 + r;
      if (l16 == 0 && node < NN) { asrcL[node] = v1; adstL[node] = v2; }
    }
  }
  __syncthreads();

  for (int layer = 0; layer < 2; ++layer) {
    for (int i = wv; i < NN; i += 16) {
      float zi = adstL[i];
      int j1 = 64 + lane;
      bool e0 = (adjPack[i][lane >> 4] >> (lane & 15)) & 1;
      bool e1 = (j1 < NN) && ((adjPack[i][j1 >> 4] >> (j1 & 15)) & 1);
      float p0 = 0.f, p1 = 0.f;
      if (e0) { float z = zi + asrcL[lane]; p0 = __expf(z > 0.f ? z : 0.2f * z); }
      if (e1) { float z = zi + asrcL[j1]; p1 = __expf(z > 0.f ? z : 0.2f * z); }
      float s = p0 + p1;
      s += __shfl_xor(s, 1); s += __shfl_xor(s, 2); s += __shfl_xor(s, 4);
      s += __shfl_xor(s, 8); s += __shfl_xor(s, 16); s += __shfl_xor(s, 32);
      float inv = 1.f / s;
      u.ly.alphaB[i * 136 + lane] = f2bf(p0 * inv);
      u.ly.alphaB[i * 136 + 64 + lane] = f2bf(p1 * inv);
    }
    __syncthreads();
    {
      const float* bias = layer ? g1b : g0b;
      for (int tile = wv; tile < 28; tile += 16) {
        int mt = tile >> 2, nt = tile & 3;
        int ar = mt * 16 + l16; if (ar > NN - 1) ar = NN - 1;
        const short* ap = &u.ly.alphaB[ar * 136 + quad * 8];
        const short* bp = hb + (nt * 16 + l16) * 128 + quad * 8;
        f32x4 acc = (f32x4){0.f, 0.f, 0.f, 0.f};
#pragma unroll
        for (int kb = 0; kb < 4; ++kb)
          acc = __builtin_amdgcn_mfma_f32_16x16x32_bf16(*(const bf16x8*)(ap + kb * 32),
                                                        *(const bf16x8*)(bp + kb * 32), acc, 0, 0, 0);
        int f = nt * 16 + l16;
        float bv = bias[f];
#pragma unroll
        for (int r = 0; r < 4; ++r) {
          int i = mt * 16 + quad * 4 + r;
          if (i < NN) u.ly.gB[i * 72 + f] = f2bf(fmaxf(acc[r] + bv, 0.f));
        }
      }
    }
    __syncthreads();
    if (layer == 0) {
      if (wv < 7) {
        int mt = wv;
        int ar = mt * 16 + l16; if (ar > NN - 1) ar = NN - 1;
        const short* ap = &u.ly.gB[ar * 72 + quad * 8];
        float s1[4] = {0.f, 0.f, 0.f, 0.f}, s2[4] = {0.f, 0.f, 0.f, 0.f};
#pragma unroll
        for (int nt = 0; nt < 4; ++nt) {
          const short* bp = w1bT + (nt * 16 + l16) * 64 + quad * 8;
          f32x4 acc = (f32x4){0.f, 0.f, 0.f, 0.f};
#pragma unroll
          for (int kb = 0; kb < 2; ++kb)
            acc = __builtin_amdgcn_mfma_f32_16x16x32_bf16(*(const bf16x8*)(ap + kb * 32),
                                                          *(const bf16x8*)(bp + kb * 32), acc, 0, 0, 0);
          int f = nt * 16 + l16;
          float a_s = g1as[f], a_d = g1ad[f];
#pragma unroll
          for (int r = 0; r < 4; ++r) {
            int node = mt * 16 + quad * 4 + r;
            if (node < NN) hb[f * 128 + node] = f2bf(acc[r]);
            s1[r] += acc[r] * a_s;
            s2[r] += acc[r] * a_d;
          }
        }
#pragma unroll
        for (int r = 0; r < 4; ++r) {
          float v1 = s1[r], v2 = s2[r];
          v1 += __shfl_xor(v1, 1); v1 += __shfl_xor(v1, 2);
          v1 += __shfl_xor(v1, 4); v1 += __shfl_xor(v1, 8);
          v2 += __shfl_xor(v2, 1); v2 += __shfl_xor(v2, 2);
          v2 += __shfl_xor(v2, 4); v2 += __shfl_xor(v2, 8);
          int node = mt * 16 + quad * 4 + r;
          if (l16 == 0 && node < NN) { asrcL[node] = v1; adstL[node] = v2; }
        }
      }
      __syncthreads();
    }
  }

  // ---- gate: gwN = sigmoid(gB @ wg2a^T + b) ----
  float* wgL = (float*)&u.ly.alphaB[0];
  float* gwN = wgL + 512;
  if (t < 512) wgL[t] = wg2a[t];
  __syncthreads();
  if (t < NN * NH) {
    int n = t >> 3, h = t & 7;
    float z = bg2a[h];
#pragma unroll
    for (int c = 0; c < GD; ++c) z += bf2f(u.ly.gB[n * 72 + c]) * wgL[h * 64 + c];
    gwN[n * 8 + h] = 1.f / (1.f + __expf(-z));
  }
  __syncthreads();

  // ---- tail: position-space gwp/gwp2 + 1024-bit posadj rows ----
  {
    int p = t;
    int n = nodeofL[p];
#pragma unroll
    for (int h = 0; h < 8; ++h) {
      float g = (n >= 0) ? gwN[n * 8 + h] : 0.f;
      gwp[(size_t)(b * 8 + h) * 1024 + p] = g;
      gwp2[(size_t)(b * 8 + h) * 1024 + p] = g * 1.4426950408889634f;
    }
    unsigned long long m[16];
#pragma unroll
    for (int w = 0; w < 16; ++w) m[w] = 0;
    if (n >= 0) {
      for (int w = 0; w < 7; ++w) {
        unsigned bits = adjPack[n][w];
        while (bits) {
          int j = __ffs(bits) - 1;
          int pj = topiL[w * 16 + j];
          m[pj >> 6] |= 1ull << (pj & 63);
          bits &= bits - 1;
        }
      }
    }
#pragma unroll
    for (int w = 0; w < 16; ++w)
      posadj[((size_t)b * 16 + w) * 1024 + p] = m[w];
  }
}

// ---------------- QKV split-bf16 MFMA GEMM (32-col tiles, LDS-staged coalesced stores) ----------------
// Q is pre-scaled by hd^-0.5 * log2(e) (attn uses exp2). V^T stored with sigma32 key permutation.
__global__ __launch_bounds__(256, 4) void qkv_k(const short* __restrict__ xth,
                                                const short* __restrict__ xtl,
                                                const short* __restrict__ wqh,
                                                const short* __restrict__ wql,
                                                short* __restrict__ qhp, short* __restrict__ qlp,
                                                short* __restrict__ khp, short* __restrict__ klp,
                                                short* __restrict__ vtp) {
  __shared__ short st_s[4][16 * 40 * 2];
  int t = threadIdx.x, wid = t >> 6, lane = t & 63, quad = lane >> 4, l16 = lane & 15;
  int m0 = blockIdx.x * 64, y = blockIdx.y;
  int b = m0 >> 10;
  int row = m0 + wid * 16 + l16;
  int p_base = (m0 & 1023) + wid * 16;
  int qi = y >> 3, n0 = (y & 7) * 32;
  const short* wh = wqh + ((size_t)qi * 256 + n0) * 256;
  const short* wl = wql + ((size_t)qi * 256 + n0) * 256;
  const short* arh = xth + (size_t)row * 256 + quad * 8;
  const short* arl = xtl + (size_t)row * 256 + quad * 8;
  f32x4 acc[2];
  acc[0] = (f32x4){0.f, 0.f, 0.f, 0.f};
  acc[1] = (f32x4){0.f, 0.f, 0.f, 0.f};
#pragma unroll
  for (int kb = 0; kb < 8; ++kb) {
    bf16x8 ah = *(const bf16x8*)(arh + kb * 32);
    bf16x8 al = *(const bf16x8*)(arl + kb * 32);
#pragma unroll
    for (int nt = 0; nt < 2; ++nt) {
      size_t wo = (size_t)(nt * 16 + l16) * 256 + kb * 32 + quad * 8;
      bf16x8 bh_ = *(const bf16x8*)(wh + wo);
      bf16x8 bl_ = *(const bf16x8*)(wl + wo);
      acc[nt] = __builtin_amdgcn_mfma_f32_16x16x32_bf16(ah, bh_, acc[nt], 0, 0, 0);
      acc[nt] = __builtin_amdgcn_mfma_f32_16x16x32_bf16(ah, bl_, acc[nt], 0, 0, 0);
      acc[nt] = __builtin_amdgcn_mfma_f32_16x16x32_bf16(al, bh_, acc[nt], 0, 0, 0);
    }
  }
  int h = n0 >> 5;
  if (qi < 2) {
    const float scale = (qi == 0) ? 0.2550348595158156f : 1.f;  // hd^-0.5 * log2(e)
    short* hp = (qi == 0) ? qhp : khp;
    short* lp = (qi == 0) ? qlp : klp;
    short* vsh = &st_s[wid][0];
    short* vsl = &st_s[wid][640];
#pragma unroll
    for (int nt = 0; nt < 2; ++nt) {
      int d = nt * 16 + l16;
#pragma unroll
      for (int r = 0; r < 4; ++r) {
        float v = acc[nt][r] * scale;
        short hi = f2bf(v);
        vsh[(quad * 4 + r) * 40 + d] = hi;
        vsl[(quad * 4 + r) * 40 + d] = f2bf(v - bf2f(hi));
      }
    }
    int orow = lane >> 2, seg = lane & 3;
    size_t e = ((size_t)(b * 8 + h) * 1024 + p_base + orow) * 32 + seg * 8;
    *(bf16x8*)(hp + e) = *(const bf16x8*)(vsh + orow * 40 + seg * 8);
    *(bf16x8*)(lp + e) = *(const bf16x8*)(vsl + orow * 40 + seg * 8);
  } else {
    // V: block-level sigma32-permuted transpose -> vt[bh][d][...]
    short* vsv = &st_s[0][0];   // 32 x 72
#pragma unroll
    for (int nt = 0; nt < 2; ++nt) {
      int d = nt * 16 + l16;
#pragma unroll
      for (int r = 0; r < 4; ++r)
        vsv[d * 72 + (quad * 4 + r) * 2 + (wid & 1) + (wid >> 1) * 32] = f2bf(acc[nt][r]);
    }
    __syncthreads();
    int d = t >> 3, g = t & 7;
    size_t rb = ((size_t)(b * 8 + h) * 32 + d) * 1024 + (m0 & 1023) + g * 8;
    *(bf16x8*)(vtp + rb) = *(const bf16x8*)(vsv + d * 72 + g * 8);
  }
}

// ---------------- flash attention: 32-key chunks, explicit-register double buffer, exp2 ----------------
__global__ __launch_bounds__(256, 4) void attn_k(const short* __restrict__ qh,
                                                 const short* __restrict__ ql,
                                                 const short* __restrict__ kh,
                                                 const short* __restrict__ kl,
                                                 const short* __restrict__ vt,
                                                 const float* __restrict__ gwp,
                                                 const float* __restrict__ gwp2,
                                                 const unsigned long long* __restrict__ posadj,
                                                 short* __restrict__ aoh,
                                                 short* __restrict__ aol) {
  __shared__ __align__(16) short p_s[4][16 * 72];  // P uses stride 40; overlay O f32 16x36
  __shared__ float aw_s[4][16];
  int t = threadIdx.x;
  int wid = t >> 6, lane = t & 63, quad = lane >> 4, l16 = lane & 15;
  int bh = blockIdx.x, b = bh >> 3, h = bh & 7;
  int q0 = blockIdx.y * 64 + wid * 16;
  size_t base = (size_t)bh * 32768;
  short* pw = &p_s[wid][0];
  float* aw = &aw_s[wid][0];

  size_t qoff = base + (size_t)(q0 + l16) * 32 + quad * 8;
  bf16x8 qhf = *(const bf16x8*)(qh + qoff);
  bf16x8 qlf = *(const bf16x8*)(ql + qoff);

  const float* gwpBH = gwp + (size_t)bh * 1024;
  const float* gwp2BH = gwp2 + (size_t)bh * 1024;
  const unsigned* pa32 = (const unsigned*)(posadj + (size_t)b * 16 * 1024);
  float grq[4];
#pragma unroll
  for (int r = 0; r < 4; ++r) grq[r] = gwp2BH[q0 + quad * 4 + r];

  f32x4 ot[2];
  ot[0] = (f32x4){0.f, 0.f, 0.f, 0.f};
  ot[1] = (f32x4){0.f, 0.f, 0.f, 0.f};
  float l_r[4] = {0.f, 0.f, 0.f, 0.f};

  // explicit double-buffered chunk fragments (NO dynamically-indexed arrays)
  bf16x8 kh0A, kh1A, kl0A, kl1A, va0A, va1A;
  bf16x8 kh0B, kh1B, kl0B, kl1B, va0B, va1B;
  float gc0A, gc1A, gc0B, gc1B;
  unsigned mrA[4], mrB[4];

#define LOADCHUNK(S, ch_)                                                          \
  {                                                                                \
    int c0_ = (ch_) * 32;                                                          \
    size_t o0_ = base + (size_t)(c0_ + l16) * 32 + quad * 8;                       \
    size_t o1_ = base + (size_t)(c0_ + 16 + l16) * 32 + quad * 8;                  \
    kh0##S = *(const bf16x8*)(kh + o0_);                                           \
    kh1##S = *(const bf16x8*)(kh + o1_);                                           \
    kl0##S = *(const bf16x8*)(kl + o0_);                                           \
    kl1##S = *(const bf16x8*)(kl + o1_);                                           \
    gc0##S = gwpBH[c0_ + l16];                                                     \
    gc1##S = gwpBH[c0_ + 16 + l16];                                                \
    va0##S = *(const bf16x8*)(vt + base + (size_t)l16 * 1024 + c0_ + quad * 8);    \
    va1##S = *(const bf16x8*)(vt + base + (size_t)(16 + l16) * 1024 + c0_ +        \
                              quad * 8);                                           \
    _Pragma("unroll")                                                              \
    for (int r = 0; r < 4; ++r)                                                    \
      mr##S[r] = pa32[(((size_t)((ch_) >> 1) * 1024) + q0 + quad * 4 + r) * 2 +    \
                      ((ch_) & 1)];                                                \
  }

#define COMPUTE(S)                                                                 \
  {                                                                                \
    f32x4 s0 = (f32x4){0.f, 0.f, 0.f, 0.f};                                        \
    f32x4 s1 = (f32x4){0.f, 0.f, 0.f, 0.f};                                        \
    s0 = __builtin_amdgcn_mfma_f32_16x16x32_bf16(qhf, kh0##S, s0, 0, 0, 0);        \
    s0 = __builtin_amdgcn_mfma_f32_16x16x32_bf16(qhf, kl0##S, s0, 0, 0, 0);        \
    s0 = __builtin_amdgcn_mfma_f32_16x16x32_bf16(qlf, kh0##S, s0, 0, 0, 0);        \
    s1 = __builtin_amdgcn_mfma_f32_16x16x32_bf16(qhf, kh1##S, s1, 0, 0, 0);        \
    s1 = __builtin_amdgcn_mfma_f32_16x16x32_bf16(qhf, kl1##S, s1, 0, 0, 0);        \
    s1 = __builtin_amdgcn_mfma_f32_16x16x32_bf16(qlf, kh1##S, s1, 0, 0, 0);        \
    _Pragma("unroll")                                                              \
    for (int r = 0; r < 4; ++r) {                                                  \
      bool b0 = (mr##S[r] >> l16) & 1u;                                            \
      bool b1 = (mr##S[r] >> (16 + l16)) & 1u;                                     \
      s0[r] += b0 ? grq[r] * gc0##S : 0.f;                                         \
      s1[r] += b1 ? grq[r] * gc1##S : 0.f;                                         \
    }                                                                              \
    _Pragma("unroll")                                                              \
    for (int r = 0; r < 4; ++r) {                                                  \
      float e0 = exp2f(s0[r]);                                                     \
      float e1 = exp2f(s1[r]);                                                     \
      l_r[r] += e0 + e1;                                                           \
      short2 pq = {f2bf(e0), f2bf(e1)};                                            \
      *(short2*)(pw + (quad * 4 + r) * 40 + l16 * 2) = pq;                         \
    }                                                                              \
    bf16x8 pb = *(const bf16x8*)(pw + l16 * 40 + quad * 8);                        \
    ot[0] = __builtin_amdgcn_mfma_f32_16x16x32_bf16(va0##S, pb, ot[0], 0, 0, 0);   \
    ot[1] = __builtin_amdgcn_mfma_f32_16x16x32_bf16(va1##S, pb, ot[1], 0, 0, 0);   \
  }

  LOADCHUNK(A, 0)
  for (int ch = 0; ch < 32; ch += 2) {
    LOADCHUNK(B, ch + 1)
    COMPUTE(A)
    if (ch + 2 < 32) LOADCHUNK(A, ch + 2)
    COMPUTE(B)
  }
#undef LOADCHUNK
#undef COMPUTE

  // final row-sum reduce, invert, transpose via per-wave LDS, hi/lo bf16 store
#pragma unroll
  for (int r = 0; r < 4; ++r) {
    float ls = l_r[r];
    ls += __shfl_xor(ls, 1);
    ls += __shfl_xor(ls, 2);
    ls += __shfl_xor(ls, 4);
    ls += __shfl_xor(ls, 8);
    if (l16 == 0) aw[quad * 4 + r] = 1.f / ls;
  }
  float li = aw[l16];
  ot[0] *= li;
  ot[1] *= li;
  float* os = (float*)pw;
#pragma unroll
  for (int mi = 0; mi < 2; ++mi)
#pragma unroll
    for (int r = 0; r < 4; ++r)
      os[l16 * 36 + mi * 16 + quad * 4 + r] = ot[mi][r];
  int qr2 = lane >> 2, dg = (lane & 3) * 8;
  float f[8];
  *(float4*)&f[0] = *(float4*)&os[qr2 * 36 + dg];
  *(float4*)&f[4] = *(float4*)&os[qr2 * 36 + dg + 4];
  bf16x8 hv, lv;
#pragma unroll
  for (int j = 0; j < 8; ++j) {
    hv[j] = f2bf(f[j]);
    lv[j] = f2bf(f[j] - bf2f(hv[j]));
  }
  size_t ob = (size_t)(b * 1024 + q0 + qr2) * 256 + h * 32 + dg;
  *(bf16x8*)(aoh + ob) = hv;
  *(bf16x8*)(aol + ob) = lv;
}

// ---------------- proj split-bf16 MFMA GEMM (32-col tiles) + bias + transposed store ----------------
__global__ __launch_bounds__(256, 4) void proj_k(const short* __restrict__ aoh,
                                                 const short* __restrict__ aol,
                                                 const short* __restrict__ wph,
                                                 const short* __restrict__ wpl,
                                                 const float* __restrict__ bias,
                                                 float* __restrict__ out) {
  __shared__ float os_s[4][32 * 20];
  int t = threadIdx.x, wid = t >> 6, lane = t & 63, quad = lane >> 4, l16 = lane & 15;
  int m0 = blockIdx.x * 64, n0 = blockIdx.y * 32;
  int b = m0 >> 10;
  int row = m0 + wid * 16 + l16;
  int p_base = (m0 & 1023) + wid * 16;
  const short* arh = aoh + (size_t)row * 256 + quad * 8;
  const short* arl = aol + (size_t)row * 256 + quad * 8;
  f32x4 acc[2];
  acc[0] = (f32x4){0.f, 0.f, 0.f, 0.f};
  acc[1] = (f32x4){0.f, 0.f, 0.f, 0.f};
#pragma unroll
  for (int kb = 0; kb < 8; ++kb) {
    bf16x8 ah = *(const bf16x8*)(arh + kb * 32);
    bf16x8 al = *(const bf16x8*)(arl + kb * 32);
#pragma unroll
    for (int nt = 0; nt < 2; ++nt) {
      size_t wo = (size_t)(n0 + nt * 16 + l16) * 256 + kb * 32 + quad * 8;
      bf16x8 bh_ = *(const bf16x8*)(wph + wo);
      bf16x8 bl_ = *(const bf16x8*)(wpl + wo);
      acc[nt] = __builtin_amdgcn_mfma_f32_16x16x32_bf16(ah, bh_, acc[nt], 0, 0, 0);
      acc[nt] = __builtin_amdgcn_mfma_f32_16x16x32_bf16(ah, bl_, acc[nt], 0, 0, 0);
      acc[nt] = __builtin_amdgcn_mfma_f32_16x16x32_bf16(al, bh_, acc[nt], 0, 0, 0);
    }
  }
  float* os = &os_s[wid][0];
#pragma unroll
  for (int nt = 0; nt < 2; ++nt) {
    float bv = bias[n0 + nt * 16 + l16];
#pragma unroll
    for (int r = 0; r < 4; ++r)
      os[(nt * 16 + l16) * 20 + quad * 4 + r] = acc[nt][r] + bv;
  }
  int cl = lane >> 1, hf = lane & 1;
  int c = n0 + cl;
  float* orow = out + ((size_t)(b * 256 + c)) * 1024 + p_base;
  *(float4*)(orow + hf * 8) = *(float4*)&os[cl * 20 + hf * 8];
  *(float4*)(orow + hf * 8 + 4) = *(float4*)&os[cl * 20 + hf * 8 + 4];
}

extern "C" void kernel_launch(void* const* d_in, const int* in_sizes, int n_in,
                              void* d_out, int out_size, void* d_ws, size_t ws_size,
                              hipStream_t stream) {
  const float* x      = (const float*)d_in[0];
  const float* w_qkv  = (const float*)d_in[1];
  const float* w_proj = (const float*)d_in[2];
  const float* b_proj = (const float*)d_in[3];
  const float* g0W    = (const float*)d_in[4];
  const float* g0as   = (const float*)d_in[5];
  const float* g0ad   = (const float*)d_in[6];
  const float* g0b    = (const float*)d_in[7];
  const float* g1W    = (const float*)d_in[8];
  const float* g1as   = (const float*)d_in[9];
  const float* g1ad   = (const float*)d_in[10];
  const float* g1b    = (const float*)d_in[11];
  const float* wg2a   = (const float*)d_in[12];
  const float* bg2a   = (const float*)d_in[13];
  float* out = (float*)d_out;
  float* ws = (float*)d_ws;

  size_t o = 0;
  auto alloc = [&](size_t nf) { float* p = ws + o; o += (nf + 15) & ~(size_t)15; return p; };
  float* imp    = alloc(8 * 1024);
  short* w0bT   = (short*)alloc(256 * 64 / 2);
  short* w1bT   = (short*)alloc(64 * 64 / 2);
  short* h0tG   = (short*)alloc(8 * 64 * 128 / 2);
  float* gwp    = alloc(64 * 1024);
  float* gwp2   = alloc(64 * 1024);
  unsigned long long* posadj = (unsigned long long*)alloc(8 * 16 * 1024 * 2);
  short* xth    = (short*)alloc(1048576);
  short* xtl    = (short*)alloc(1048576);
  short* wqh    = (short*)alloc(98304);
  short* wql    = (short*)alloc(98304);
  short* wph    = (short*)alloc(32768);
  short* wpl    = (short*)alloc(32768);
  short* qh     = (short*)alloc(1048576);
  short* ql     = (short*)alloc(1048576);
  short* kh     = (short*)alloc(1048576);
  short* kl     = (short*)alloc(1048576);
  short* vt     = (short*)alloc(1048576);
  short* aoh    = (short*)alloc(1048576);
  short* aol    = (short*)alloc(1048576);
  if (ws_size < o * sizeof(float)) return;

  importance_k<<<256, 256, 0, stream>>>(x, imp);
  wsplitprep_k<<<1104, 256, 0, stream>>>(w_qkv, w_proj, g0W, g1W,
                                         wqh, wql, wph, wpl, w0bT, w1bT);
  xsplit_k<<<dim3(16, 4, 8), 256, 0, stream>>>(x, xth, xtl);
  graph_k<<<8, 1024, 0, stream>>>(imp, xth, xtl, w0bT, w1bT,
                                  g0as, g0ad, g0b, g1as, g1ad, g1b,
                                  wg2a, bg2a, h0tG, gwp, gwp2, posadj);
  qkv_k<<<dim3(128, 24), 256, 0, stream>>>(xth, xtl, wqh, wql, qh, ql, kh, kl, vt);
  attn_k<<<dim3(64, 16), 256, 0, stream>>>(qh, ql, kh, kl, vt, gwp, gwp2, posadj, aoh, aol);
  proj_k<<<dim3(128, 8), 256, 0, stream>>>(aoh, aol, wph, wpl, b_proj, out);
}